// Round 6
// baseline (5583.646 us; speedup 1.0000x reference)
//
#include <hip/hip_runtime.h>
#include <math.h>

#define BSZ 64
#define TLEN 256
#define LSND 65536
#define ZK 160            // z K-length in bf16 slots: 129 real + iv-residual@129 + pads

typedef __attribute__((ext_vector_type(8))) short bf16x8;
typedef __attribute__((ext_vector_type(4))) float f32x4;

__device__ __forceinline__ float sigm(float x) { return 1.f / (1.f + __expf(-x)); }
__device__ __forceinline__ float tanh_f(float x) {
  float e = __expf(-2.f * fabsf(x));
  return copysignf((1.f - e) / (1.f + e), x);
}
__device__ __forceinline__ unsigned short f2bf(float x) {   // RNE f32->bf16
  unsigned u = __float_as_uint(x);
  return (unsigned short)((u + 0x7FFFu + ((u >> 16) & 1u)) >> 16);
}

// K1: fold linear into w_ih: Wc[n][j] (1024x132, cols>=129 zero); bc = folded bias
__global__ __launch_bounds__(256) void prep_kernel(
    const float* __restrict__ w_ih, const float* __restrict__ lin_w,
    const float* __restrict__ lin_b, const float* __restrict__ b_ih,
    const float* __restrict__ b_hh, float* __restrict__ Wc, float* __restrict__ bc)
{
  __shared__ float sRow[256];
  const int n = blockIdx.x;
  const int j = threadIdx.x;
  sRow[j] = w_ih[n * 256 + j];
  __syncthreads();
  if (j < 132) {
    float acc = 0.f;
    if (j < 129) {
      for (int k = 0; k < 256; ++k) acc += sRow[k] * lin_w[k * 129 + j];
    }
    Wc[n * 132 + j] = acc;
  } else if (j == 255) {
    float acc = b_ih[n] + b_hh[n];
    for (int k = 0; k < 256; ++k) acc += sRow[k] * lin_b[k];
    bc[n] = acc;
  }
}

__global__ __launch_bounds__(256) void transpose_w3(const float* __restrict__ w3,
                                                    float* __restrict__ w3t)
{
  int i = blockIdx.x * 256 + threadIdx.x;
  if (i < 96 * 128) { int s = i >> 7, o = i & 127; w3t[i] = w3[o * 96 + s]; }
}

// K2: gather + conv1/conv2/conv3 -> zw[t][b][ZK] bf16.
// feature 0 = bf16(interval); feature 129 = residual (interval - bf16(interval));
// features 1..128 = y3; 130..159 zero pad.
__global__ __launch_bounds__(64) void conv_kernel(
    const int* __restrict__ alpha, const float* __restrict__ sound,
    const float* __restrict__ w1, const float* __restrict__ b1v,
    const float* __restrict__ w2, const float* __restrict__ b2,
    const float* __restrict__ w3t, const float* __restrict__ b3,
    unsigned short* __restrict__ zw)
{
  __shared__ float win[2048];
  __shared__ float sY2[96];
  const int l = threadIdx.x;
  const int b = blockIdx.x >> 8;
  const int t = blockIdx.x & 255;
  const int a = alpha[b * TLEN + t];
  const int a0 = a - 1024;
  const float* srow = sound + (size_t)b * LSND;
  for (int x = l; x < 2048; x += 64) {
    int p = a0 + x;
    win[x] = (p >= 0 && p < LSND) ? srow[p] : 0.f;
  }
  __syncthreads();
  float acc0 = 0.f, acc1 = 0.f, acc2 = 0.f;
  for (int f = l; f < 2046; f += 64) {
    float wv = w1[f];
    acc0 += win[f] * wv;
    acc1 += win[f + 1] * wv;
    acc2 += win[f + 2] * wv;
  }
  for (int m = 32; m; m >>= 1) {
    acc0 += __shfl_xor(acc0, m);
    acc1 += __shfl_xor(acc1, m);
    acc2 += __shfl_xor(acc2, m);
  }
  const float bb = b1v[0];
  const float y11 = acc0 + bb, y12 = acc1 + bb, y13 = acc2 + bb;
  {
    int s = l;
    int c = s / 3, lp = s - c * 3;
    float wA = w2[c * 3], wB = w2[c * 3 + 1], wC = w2[c * 3 + 2];
    float v = (lp == 0) ? (y11 * wB + y12 * wC)
            : (lp == 1) ? (y11 * wA + y12 * wB + y13 * wC)
                        : (y12 * wA + y13 * wB);
    sY2[s] = fmaxf(v + b2[c], 0.f);
    if (l < 32) {
      s = 64 + l; c = s / 3; lp = s - c * 3;
      wA = w2[c * 3]; wB = w2[c * 3 + 1]; wC = w2[c * 3 + 2];
      v = (lp == 0) ? (y11 * wB + y12 * wC)
        : (lp == 1) ? (y11 * wA + y12 * wB + y13 * wC)
                    : (y12 * wA + y13 * wB);
      sY2[s] = fmaxf(v + b2[c], 0.f);
    }
  }
  __syncthreads();
  float o0 = b3[l], o1 = b3[l + 64];
  for (int s = 0; s < 96; ++s) {
    float yv = sY2[s];
    o0 += yv * w3t[s * 128 + l];
    o1 += yv * w3t[s * 128 + l + 64];
  }
  unsigned short* zrow = zw + ((size_t)t * BSZ + b) * ZK;
  zrow[1 + l] = f2bf(o0);
  zrow[65 + l] = f2bf(o1);
  if (l == 0) {
    int prev = (t > 0) ? alpha[b * TLEN + t - 1] : 0;
    float iv = (float)(a - prev);
    unsigned short hi = f2bf(iv);
    zrow[0] = hi;
    float rec = __uint_as_float(((unsigned)hi) << 16);
    zrow[129] = f2bf(iv - rec);
  }
  if (l < 30) zrow[130 + l] = 0;
}

// K3: fully block-local MFMA LSTM. 4 blocks x 1024 threads; block bt owns batches
// [bt*16,+16) and ALL 1024 gate rows -> the recurrence never leaves the CU.
// All weights [w_hh | Wc] live in VGPRs as A-fragments (4 tiles/wave x 13 k-frags,
// 208 VGPR/lane). Wave w owns j-quads 4w..4w+3 (A-tile row m -> jl=m>>2, gate=m&3,
// so the HW C/D map col=lane&15,row=(lane>>4)*4+reg gives each lane all 4 gates of
// one (j,b): gate math is lane-local). h recirculates through 16KB LDS: rows [b],
// 256 bf16 j's, 16B-slot XOR-swizzled (slot s -> s^bl) so B-frag ds_read_b128 and
// h ds_write_b16 are uniformly spread across banks. One __syncthreads per step;
// zero global traffic in the loop except cached z prefetch (2 steps ahead).
__global__ void __launch_bounds__(1024) lstm_kernel(
    const unsigned short* __restrict__ zw, const float* __restrict__ Wc,
    const float* __restrict__ bc, const float* __restrict__ w_hh,
    float* __restrict__ hfin)
{
  __shared__ unsigned short sH[2][16][256];   // [parity][b][j] (swizzled)
  char* sHb = (char*)&sH[0][0][0];

  const int tid = threadIdx.x;
  const int w  = tid >> 6;            // wave 0..15
  const int ln = tid & 63;
  const int bl = ln & 15;             // b lane / A-row lane / B-col lane
  const int kg = ln >> 4;             // k-group; also jl of this lane's outputs
  const int bt = (int)blockIdx.x;     // 0..3
  const int b  = (bt << 4) + bl;

  // ---- A fragments: 4 tiles (j-quads 4w+a), rows m=bl -> (jl=m>>2, gate=m&3) ----
  bf16x8 afr[4][13];
  #pragma unroll
  for (int a = 0; a < 4; ++a) {
    const int jA   = (w << 4) + (a << 2) + (bl >> 2);
    const int grow = ((bl & 3) << 8) + jA;
    #pragma unroll
    for (int o = 0; o < 13; ++o) {
      #pragma unroll
      for (int e = 0; e < 8; ++e) {
        const int k = o * 32 + kg * 8 + e;
        float wt;
        if (k < 256) wt = w_hh[grow * 256 + k];
        else {
          const int kz = k - 256;
          wt = (kz < 129) ? Wc[grow * 132 + kz] : (kz == 129 ? Wc[grow * 132] : 0.f);
        }
        afr[a][o][e] = (short)f2bf(wt);
      }
    }
  }
  float bias[4][4];
  #pragma unroll
  for (int a = 0; a < 4; ++a)
    #pragma unroll
    for (int r = 0; r < 4; ++r)
      bias[a][r] = bc[(r << 8) + (w << 4) + (a << 2) + kg];

  // ---- zero h(0) in LDS ----
  {
    unsigned* s32 = (unsigned*)sHb;
    for (int i = tid; i < 4096; i += 1024) s32[i] = 0;
  }

  // ---- z fragment double buffer (t and t+1) ----
  bf16x8 zA[5], zB[5];
  #pragma unroll
  for (int o = 0; o < 5; ++o) {
    zA[o] = *(const bf16x8*)(zw + ((size_t)0 * BSZ + b) * ZK + o * 32 + kg * 8);
    zB[o] = *(const bf16x8*)(zw + ((size_t)1 * BSZ + b) * ZK + o * 32 + kg * 8);
  }
  float cs[4] = {0.f, 0.f, 0.f, 0.f};
  __syncthreads();

#define STEP(T, ZC)                                                             \
  {                                                                             \
    const int t_ = (T);                                                         \
    const int p_ = (t_ & 1) << 13;        /* parity byte offset */              \
    bf16x8 hfr[8];                                                              \
    _Pragma("unroll")                                                           \
    for (int o = 0; o < 8; ++o)                                                 \
      hfr[o] = *(const bf16x8*)(sHb + p_ + (bl << 9) + (((o * 4 + kg) ^ bl) << 4)); \
    f32x4 acc[4];                                                               \
    _Pragma("unroll")                                                           \
    for (int a = 0; a < 4; ++a) {                                               \
      acc[a][0] = bias[a][0]; acc[a][1] = bias[a][1];                           \
      acc[a][2] = bias[a][2]; acc[a][3] = bias[a][3];                           \
    }                                                                           \
    _Pragma("unroll")                                                           \
    for (int o = 0; o < 5; ++o) {                                               \
      _Pragma("unroll")                                                         \
      for (int a = 0; a < 4; ++a)                                               \
        acc[a] = __builtin_amdgcn_mfma_f32_16x16x32_bf16(afr[a][8 + o], ZC[o],  \
                                                         acc[a], 0, 0, 0);      \
    }                                                                           \
    _Pragma("unroll")                                                           \
    for (int o = 0; o < 8; ++o) {                                               \
      _Pragma("unroll")                                                         \
      for (int a = 0; a < 4; ++a)                                               \
        acc[a] = __builtin_amdgcn_mfma_f32_16x16x32_bf16(afr[a][o], hfr[o],     \
                                                         acc[a], 0, 0, 0);      \
    }                                                                           \
    _Pragma("unroll")                                                           \
    for (int a = 0; a < 4; ++a) {                                               \
      cs[a] = sigm(acc[a][1]) * cs[a] + sigm(acc[a][0]) * tanh_f(acc[a][2]);    \
      const float hv = sigm(acc[a][3]) * tanh_f(cs[a]);                         \
      if (t_ < TLEN - 1) {                                                      \
        /* j = 16w+4a+kg -> slot s = 2w+(a>>1), in-slot byte = ((a&1)<<3)+(kg<<1) */ \
        char* wb = sHb + (p_ ^ 8192) + (bl << 9)                                \
                 + ((((w << 1) + (a >> 1)) ^ bl) << 4)                          \
                 + (((a & 1) << 3) + (kg << 1));                                \
        *(unsigned short*)wb = f2bf(hv);                                        \
      } else {                                                                  \
        hfin[b * 256 + (w << 4) + (a << 2) + kg] = hv;                          \
      }                                                                         \
    }                                                                           \
    if (t_ < TLEN - 1) {                                                        \
      if (t_ + 2 < TLEN) {                                                      \
        _Pragma("unroll")                                                       \
        for (int o = 0; o < 5; ++o)                                             \
          ZC[o] = *(const bf16x8*)(zw + ((size_t)(t_ + 2) * BSZ + b) * ZK       \
                                   + o * 32 + kg * 8);                          \
      }                                                                         \
      __syncthreads();                                                          \
    }                                                                           \
  }

  #pragma unroll 1
  for (int t = 0; t < TLEN; t += 2) {
    STEP(t,     zA)
    STEP(t + 1, zB)
  }
#undef STEP
}

// K4: head
__global__ __launch_bounds__(256) void head_kernel(
    const float* __restrict__ hfin, const float* __restrict__ o1w,
    const float* __restrict__ o1b, const float* __restrict__ o2w,
    const float* __restrict__ o2b, float* __restrict__ out)
{
  __shared__ float sR[32];
  const int b = blockIdx.x;
  const int tid = threadIdx.x;
  const int m = tid >> 3, g = tid & 7;
  const float* h = hfin + b * 256;
  float acc = 0.f;
  for (int k = g * 32; k < g * 32 + 32; ++k) acc += h[k] * o1w[m * 256 + k];
  acc += __shfl_xor(acc, 1); acc += __shfl_xor(acc, 2); acc += __shfl_xor(acc, 4);
  if (g == 0) sR[m] = fmaxf(acc + o1b[m], 0.f);
  __syncthreads();
  if (tid == 0) {
    float s = o2b[0];
    for (int mm = 0; mm < 32; ++mm) s += sR[mm] * o2w[mm];
    out[b] = sigm(s);
  }
}

extern "C" void kernel_launch(void* const* d_in, const int* in_sizes, int n_in,
                              void* d_out, int out_size, void* d_ws, size_t ws_size,
                              hipStream_t stream) {
  (void)in_sizes; (void)n_in; (void)out_size; (void)ws_size;
  const int*   alpha = (const int*)  d_in[0];
  const float* sound = (const float*)d_in[1];
  const float* w1    = (const float*)d_in[2];
  const float* b1    = (const float*)d_in[3];
  const float* w2    = (const float*)d_in[4];
  const float* b2    = (const float*)d_in[5];
  const float* w3    = (const float*)d_in[6];
  const float* b3    = (const float*)d_in[7];
  const float* linw  = (const float*)d_in[8];
  const float* linb  = (const float*)d_in[9];
  const float* wih   = (const float*)d_in[10];
  const float* whh   = (const float*)d_in[11];
  const float* bih   = (const float*)d_in[12];
  const float* bhh   = (const float*)d_in[13];
  const float* o1w   = (const float*)d_in[14];
  const float* o1b   = (const float*)d_in[15];
  const float* o2w   = (const float*)d_in[16];
  const float* o2b   = (const float*)d_in[17];

  // byte layout (16B-aligned)
  char* p = (char*)d_ws;
  unsigned short* zw   = (unsigned short*)p;               // 256*64*160 u16 = 5,242,880 B
  float*          Wc   = (float*)(p + 5242880);            // 1024*132 f     =   540,672 B
  float*          bc   = (float*)(p + 5783552);            //                      4,096 B
  float*          w3t  = (float*)(p + 5787648);            //                     49,152 B
  float*          hfin = (float*)(p + 5836800);            //                     65,536 B

  prep_kernel<<<1024, 256, 0, stream>>>(wih, linw, linb, bih, bhh, Wc, bc);
  transpose_w3<<<48, 256, 0, stream>>>(w3, w3t);
  conv_kernel<<<BSZ * TLEN, 64, 0, stream>>>(alpha, sound, w1, b1, w2, b2, w3t, b3, zw);
  lstm_kernel<<<4, 1024, 0, stream>>>(zw, Wc, bc, whh, hfin);
  head_kernel<<<BSZ, 256, 0, stream>>>(hfin, o1w, o1b, o2w, o2b, (float*)d_out);
}

// Round 7
// 1191.398 us; speedup vs baseline: 4.6866x; 4.6866x over previous
//
#include <hip/hip_runtime.h>
#include <math.h>

#define BSZ 64
#define TLEN 256
#define LSND 65536
#define ZK 160            // z K-length in bf16 slots: 129 real + iv-residual@129 + pads

typedef __attribute__((ext_vector_type(8))) short bf16x8;
typedef __attribute__((ext_vector_type(4))) float f32x4;

__device__ __forceinline__ float sigm(float x) { return 1.f / (1.f + __expf(-x)); }
__device__ __forceinline__ float tanh_f(float x) {
  float e = __expf(-2.f * fabsf(x));
  return copysignf((1.f - e) / (1.f + e), x);
}
__device__ __forceinline__ unsigned short f2bf(float x) {   // RNE f32->bf16
  unsigned u = __float_as_uint(x);
  return (unsigned short)((u + 0x7FFFu + ((u >> 16) & 1u)) >> 16);
}

union ZB { bf16x8 v; };

// K1: fold linear into w_ih: Wc[n][j] (1024x132, cols>=129 zero); bc = folded bias
__global__ __launch_bounds__(256) void prep_kernel(
    const float* __restrict__ w_ih, const float* __restrict__ lin_w,
    const float* __restrict__ lin_b, const float* __restrict__ b_ih,
    const float* __restrict__ b_hh, float* __restrict__ Wc, float* __restrict__ bc)
{
  __shared__ float sRow[256];
  const int n = blockIdx.x;
  const int j = threadIdx.x;
  sRow[j] = w_ih[n * 256 + j];
  __syncthreads();
  if (j < 132) {
    float acc = 0.f;
    if (j < 129) {
      for (int k = 0; k < 256; ++k) acc += sRow[k] * lin_w[k * 129 + j];
    }
    Wc[n * 132 + j] = acc;
  } else if (j == 255) {
    float acc = b_ih[n] + b_hh[n];
    for (int k = 0; k < 256; ++k) acc += sRow[k] * lin_b[k];
    bc[n] = acc;
  }
}

__global__ __launch_bounds__(256) void transpose_w3(const float* __restrict__ w3,
                                                    float* __restrict__ w3t)
{
  int i = blockIdx.x * 256 + threadIdx.x;
  if (i < 96 * 128) { int s = i >> 7, o = i & 127; w3t[i] = w3[o * 96 + s]; }
}

// K2: gather + conv1/conv2/conv3 -> zw[t][b][ZK] bf16.
// feature 0 = bf16(interval); feature 129 = residual (interval - bf16(interval));
// features 1..128 = y3; 130..159 zero pad.
__global__ __launch_bounds__(64) void conv_kernel(
    const int* __restrict__ alpha, const float* __restrict__ sound,
    const float* __restrict__ w1, const float* __restrict__ b1v,
    const float* __restrict__ w2, const float* __restrict__ b2,
    const float* __restrict__ w3t, const float* __restrict__ b3,
    unsigned short* __restrict__ zw)
{
  __shared__ float win[2048];
  __shared__ float sY2[96];
  const int l = threadIdx.x;
  const int b = blockIdx.x >> 8;
  const int t = blockIdx.x & 255;
  const int a = alpha[b * TLEN + t];
  const int a0 = a - 1024;
  const float* srow = sound + (size_t)b * LSND;
  for (int x = l; x < 2048; x += 64) {
    int p = a0 + x;
    win[x] = (p >= 0 && p < LSND) ? srow[p] : 0.f;
  }
  __syncthreads();
  float acc0 = 0.f, acc1 = 0.f, acc2 = 0.f;
  for (int f = l; f < 2046; f += 64) {
    float wv = w1[f];
    acc0 += win[f] * wv;
    acc1 += win[f + 1] * wv;
    acc2 += win[f + 2] * wv;
  }
  for (int m = 32; m; m >>= 1) {
    acc0 += __shfl_xor(acc0, m);
    acc1 += __shfl_xor(acc1, m);
    acc2 += __shfl_xor(acc2, m);
  }
  const float bb = b1v[0];
  const float y11 = acc0 + bb, y12 = acc1 + bb, y13 = acc2 + bb;
  {
    int s = l;
    int c = s / 3, lp = s - c * 3;
    float wA = w2[c * 3], wB = w2[c * 3 + 1], wC = w2[c * 3 + 2];
    float v = (lp == 0) ? (y11 * wB + y12 * wC)
            : (lp == 1) ? (y11 * wA + y12 * wB + y13 * wC)
                        : (y12 * wA + y13 * wB);
    sY2[s] = fmaxf(v + b2[c], 0.f);
    if (l < 32) {
      s = 64 + l; c = s / 3; lp = s - c * 3;
      wA = w2[c * 3]; wB = w2[c * 3 + 1]; wC = w2[c * 3 + 2];
      v = (lp == 0) ? (y11 * wB + y12 * wC)
        : (lp == 1) ? (y11 * wA + y12 * wB + y13 * wC)
                    : (y12 * wA + y13 * wB);
      sY2[s] = fmaxf(v + b2[c], 0.f);
    }
  }
  __syncthreads();
  float o0 = b3[l], o1 = b3[l + 64];
  for (int s = 0; s < 96; ++s) {
    float yv = sY2[s];
    o0 += yv * w3t[s * 128 + l];
    o1 += yv * w3t[s * 128 + l + 64];
  }
  unsigned short* zrow = zw + ((size_t)t * BSZ + b) * ZK;
  zrow[1 + l] = f2bf(o0);
  zrow[65 + l] = f2bf(o1);
  if (l == 0) {
    int prev = (t > 0) ? alpha[b * TLEN + t - 1] : 0;
    float iv = (float)(a - prev);
    unsigned short hi = f2bf(iv);
    zrow[0] = hi;
    float rec = __uint_as_float(((unsigned)hi) << 16);
    zrow[129] = f2bf(iv - rec);
  }
  if (l < 30) zrow[130 + l] = 0;
}

// K3: MFMA LSTM across 16 blocks (jt 0..3 x bt 0..3) x 512 threads (8 waves,
// __launch_bounds__(512,2) -> 256-VGPR cap). Block owns 64 j's x 4 gates x 16 b;
// weight slice (256 rows x K=416) register-resident: 2 A-tiles/wave x 13 frags
// = 104 VGPR/lane. Tile rows m = jl*4+gate so HW C/D (col=lane&15,
// row=(lane>>4)*4+reg) makes gate math lane-local (R4/R5-verified mapping).
// h exchange: single-phase tagged u64 mailboxes {tag32 | 2xbf16} via relaxed
// agent-scope atomics (L3, bypass L1/L2) - payload rides the polling load.
// Each of the block's 2048 words polled by EXACTLY ONE lane (4/lane), fanned
// out via 8KB XOR-swizzled LDS, one __syncthreads/step. 3-buffer rotation is
// causally overwrite-safe. z B-frags load before the poll (latency hidden).
__global__ void __launch_bounds__(512, 2) lstm_kernel(
    const unsigned short* __restrict__ zw, const float* __restrict__ Wc,
    const float* __restrict__ bc, const float* __restrict__ w_hh,
    unsigned long long* __restrict__ hq, float* __restrict__ hfin)
{
  __shared__ uint4 sH[2][16][32];     // [parity][b_local][j-octet slot] (swizzled)
  char* sHb = (char*)&sH[0][0][0];

  const int tid = threadIdx.x;
  const int w  = tid >> 6;            // wave 0..7
  const int ln = tid & 63;
  const int bl = ln & 15;             // A-row lane / B-col lane (local b)
  const int kg = ln >> 4;             // k-group; also jl of this lane's outputs
  const int jt = (int)blockIdx.x & 3;   // j-quarter: j in [jt*64, +64)
  const int bt = (int)blockIdx.x >> 2;  // b-quarter: b in [bt*16, +16)
  const int b  = (bt << 4) + bl;

  // ---- A fragments: 2 tiles (row m = jl*4+gate), k-pack matches B ----
  bf16x8 afr[2][13];
  #pragma unroll
  for (int a = 0; a < 2; ++a) {
    const int jloc = ((w << 1) + a) * 4 + (bl >> 2);       // j within quarter
    const int grow = (bl & 3) * 256 + jt * 64 + jloc;      // original weight row
    #pragma unroll
    for (int o = 0; o < 13; ++o) {
      #pragma unroll
      for (int e = 0; e < 8; ++e) {
        const int k = o * 32 + kg * 8 + e;
        float wt;
        if (k < 256) wt = w_hh[grow * 256 + k];
        else {
          const int kz = k - 256;
          wt = (kz < 129) ? Wc[grow * 132 + kz] : (kz == 129 ? Wc[grow * 132] : 0.f);
        }
        afr[a][o][e] = (short)f2bf(wt);
      }
    }
  }
  float bias[2][4];
  #pragma unroll
  for (int a = 0; a < 2; ++a)
    #pragma unroll
    for (int r = 0; r < 4; ++r)
      bias[a][r] = bc[r * 256 + jt * 64 + ((w << 1) + a) * 4 + kg];

  // poll role: lane covers j-octet oct for local batch bloc
  const int bloc = tid >> 5;          // 0..15
  const int oct  = tid & 31;          // 0..31
  const int pollbase = ((bt << 4) + bloc) * 128 + (oct << 2);
  char* ldsW = sHb + (bloc << 9) + (((oct ^ bloc) & 31) << 4);
  float cs[2] = {0.f, 0.f};

  #pragma unroll 1
  for (int t = 0; t < TLEN; ++t) {
    const int parity = (t & 1) << 13;           // LDS byte offset
    const int bufR = t % 3, bufW = (t + 1) % 3;

    // ---- z B-frags for this step (issued first; poll hides their latency) ----
    bf16x8 zf[5];
    #pragma unroll
    for (int oz = 0; oz < 5; ++oz)
      zf[oz] = *(const bf16x8*)(zw + ((size_t)t * BSZ + b) * ZK + oz * 32 + kg * 8);

    // ---- poll: 4 distinct tagged words per lane; payload rides the load ----
    {
      const unsigned long long* hs = hq + (size_t)bufR * 8192 + pollbase;
      const unsigned tagw = (unsigned)t;
      unsigned long long v0, v1, v2, v3;
      v0 = __hip_atomic_load(hs + 0, __ATOMIC_RELAXED, __HIP_MEMORY_SCOPE_AGENT);
      v1 = __hip_atomic_load(hs + 1, __ATOMIC_RELAXED, __HIP_MEMORY_SCOPE_AGENT);
      v2 = __hip_atomic_load(hs + 2, __ATOMIC_RELAXED, __HIP_MEMORY_SCOPE_AGENT);
      v3 = __hip_atomic_load(hs + 3, __ATOMIC_RELAXED, __HIP_MEMORY_SCOPE_AGENT);
      for (;;) {
        bool ok = true;
        if ((unsigned)(v0 >> 32) != tagw) {
          v0 = __hip_atomic_load(hs + 0, __ATOMIC_RELAXED, __HIP_MEMORY_SCOPE_AGENT); ok = false; }
        if ((unsigned)(v1 >> 32) != tagw) {
          v1 = __hip_atomic_load(hs + 1, __ATOMIC_RELAXED, __HIP_MEMORY_SCOPE_AGENT); ok = false; }
        if ((unsigned)(v2 >> 32) != tagw) {
          v2 = __hip_atomic_load(hs + 2, __ATOMIC_RELAXED, __HIP_MEMORY_SCOPE_AGENT); ok = false; }
        if ((unsigned)(v3 >> 32) != tagw) {
          v3 = __hip_atomic_load(hs + 3, __ATOMIC_RELAXED, __HIP_MEMORY_SCOPE_AGENT); ok = false; }
        if (ok) break;
      }
      uint4 pay;
      pay.x = (unsigned)v0; pay.y = (unsigned)v1;
      pay.z = (unsigned)v2; pay.w = (unsigned)v3;
      *(uint4*)(ldsW + parity) = pay;           // j-octet, swizzled slot
    }
    __syncthreads();

    // ---- MFMA: z-part first (regs ready), then h-part from LDS ----
    f32x4 acc0, acc1;
    acc0[0] = bias[0][0]; acc0[1] = bias[0][1]; acc0[2] = bias[0][2]; acc0[3] = bias[0][3];
    acc1[0] = bias[1][0]; acc1[1] = bias[1][1]; acc1[2] = bias[1][2]; acc1[3] = bias[1][3];
    #pragma unroll
    for (int oz = 0; oz < 5; ++oz) {
      acc0 = __builtin_amdgcn_mfma_f32_16x16x32_bf16(afr[0][8 + oz], zf[oz], acc0, 0, 0, 0);
      acc1 = __builtin_amdgcn_mfma_f32_16x16x32_bf16(afr[1][8 + oz], zf[oz], acc1, 0, 0, 0);
    }
    #pragma unroll
    for (int o = 0; o < 8; ++o) {
      bf16x8 hf = *(const bf16x8*)(sHb + parity + (bl << 9) + ((((o << 2) + kg) ^ bl) << 4));
      acc0 = __builtin_amdgcn_mfma_f32_16x16x32_bf16(afr[0][o], hf, acc0, 0, 0, 0);
      acc1 = __builtin_amdgcn_mfma_f32_16x16x32_bf16(afr[1][o], hf, acc1, 0, 0, 0);
    }

    // ---- gates (lane-local) + publish ----
    #pragma unroll
    for (int a = 0; a < 2; ++a) {
      const f32x4 acc = a ? acc1 : acc0;
      cs[a] = sigm(acc[1]) * cs[a] + sigm(acc[0]) * tanh_f(acc[2]);
      const float hv = sigm(acc[3]) * tanh_f(cs[a]);
      const float hp = __shfl_xor(hv, 16);      // partner kg^1
      const int j = jt * 64 + ((w << 1) + a) * 4 + kg;
      if (t < TLEN - 1) {
        if (!(kg & 1)) {
          const unsigned d = (unsigned)f2bf(hv) | ((unsigned)f2bf(hp) << 16);
          const unsigned long long pk = ((unsigned long long)(unsigned)(t + 1) << 32) | d;
          __hip_atomic_store(hq + (size_t)bufW * 8192 + (size_t)b * 128 + (j >> 1),
                             pk, __ATOMIC_RELAXED, __HIP_MEMORY_SCOPE_AGENT);
        }
      } else {
        hfin[b * 256 + j] = hv;
      }
    }
  }
}

// K4: head
__global__ __launch_bounds__(256) void head_kernel(
    const float* __restrict__ hfin, const float* __restrict__ o1w,
    const float* __restrict__ o1b, const float* __restrict__ o2w,
    const float* __restrict__ o2b, float* __restrict__ out)
{
  __shared__ float sR[32];
  const int b = blockIdx.x;
  const int tid = threadIdx.x;
  const int m = tid >> 3, g = tid & 7;
  const float* h = hfin + b * 256;
  float acc = 0.f;
  for (int k = g * 32; k < g * 32 + 32; ++k) acc += h[k] * o1w[m * 256 + k];
  acc += __shfl_xor(acc, 1); acc += __shfl_xor(acc, 2); acc += __shfl_xor(acc, 4);
  if (g == 0) sR[m] = fmaxf(acc + o1b[m], 0.f);
  __syncthreads();
  if (tid == 0) {
    float s = o2b[0];
    for (int mm = 0; mm < 32; ++mm) s += sR[mm] * o2w[mm];
    out[b] = sigm(s);
  }
}

extern "C" void kernel_launch(void* const* d_in, const int* in_sizes, int n_in,
                              void* d_out, int out_size, void* d_ws, size_t ws_size,
                              hipStream_t stream) {
  (void)in_sizes; (void)n_in; (void)out_size; (void)ws_size;
  const int*   alpha = (const int*)  d_in[0];
  const float* sound = (const float*)d_in[1];
  const float* w1    = (const float*)d_in[2];
  const float* b1    = (const float*)d_in[3];
  const float* w2    = (const float*)d_in[4];
  const float* b2    = (const float*)d_in[5];
  const float* w3    = (const float*)d_in[6];
  const float* b3    = (const float*)d_in[7];
  const float* linw  = (const float*)d_in[8];
  const float* linb  = (const float*)d_in[9];
  const float* wih   = (const float*)d_in[10];
  const float* whh   = (const float*)d_in[11];
  const float* bih   = (const float*)d_in[12];
  const float* bhh   = (const float*)d_in[13];
  const float* o1w   = (const float*)d_in[14];
  const float* o1b   = (const float*)d_in[15];
  const float* o2w   = (const float*)d_in[16];
  const float* o2b   = (const float*)d_in[17];

  // byte layout (16B-aligned)
  char* p = (char*)d_ws;
  unsigned short* zw   = (unsigned short*)p;               // 256*64*160 u16 = 5,242,880 B
  float*          Wc   = (float*)(p + 5242880);            // 1024*132 f     =   540,672 B
  float*          bc   = (float*)(p + 5783552);            //                      4,096 B
  float*          w3t  = (float*)(p + 5787648);            //                     49,152 B
  float*          hfin = (float*)(p + 5836800);            //                     65,536 B
  unsigned long long* hq =
      (unsigned long long*)(p + 5902336);                  // 3*64*128 u64   =   196,608 B

  hipMemsetAsync(p + 5902336, 0, 196608, stream);          // buf0: tag0, h0=0

  prep_kernel<<<1024, 256, 0, stream>>>(wih, linw, linb, bih, bhh, Wc, bc);
  transpose_w3<<<48, 256, 0, stream>>>(w3, w3t);
  conv_kernel<<<BSZ * TLEN, 64, 0, stream>>>(alpha, sound, w1, b1, w2, b2, w3t, b3, zw);
  lstm_kernel<<<16, 512, 0, stream>>>(zw, Wc, bc, whh, hq, hfin);
  head_kernel<<<BSZ, 256, 0, stream>>>(hfin, o1w, o1b, o2w, o2b, (float*)d_out);
}